// Round 11
// baseline (27671.124 us; speedup 1.0000x reference)
//
#include <hip/hip_runtime.h>
#include <cstdint>

#define T_STEPS 8192
#define HDIM    1024
#define NBLK    256
#define NTHR    256

typedef float        f32x4 __attribute__((ext_vector_type(4)));
typedef unsigned int u32x4 __attribute__((ext_vector_type(4)));

__device__ __forceinline__ float dot4(f32x4 a, f32x4 b) {
    return a[0] * b[0] + a[1] * b[1] + a[2] * b[2] + a[3] * b[3];
}
__device__ __forceinline__ float sigmoidf_(float v) { return 1.0f / (1.0f + __expf(-v)); }
__device__ __forceinline__ float tanhf_(float v)    { return 1.0f - 2.0f / (__expf(2.0f * v) + 1.0f); }
__device__ __forceinline__ unsigned bf16_rne(float f) {
    unsigned b = __float_as_uint(f);
    return (b + 0x7FFFu + ((b >> 16) & 1u)) >> 16;
}

// ======== phase 1: gxT[b][t][r][q] = x[t]·W_ih[1024q + 4b + r] + bias ========
// Layout change vs R4/R9: inner 16 = [unit_local r][gate q] so the loop's
// wave w reads its unit's 4 gx floats as ONE broadcast dwordx4 (no shuffles).
__global__ __launch_bounds__(256)
void gemm_gx(const float* __restrict__ x, const float* __restrict__ W_ih,
             const float* __restrict__ b_ih, const float* __restrict__ b_hh,
             float* __restrict__ gxT)
{
    __shared__ float a_s[16][68];
    __shared__ float b_s[16][68];
    const int t  = threadIdx.x;
    const int bm = blockIdx.x >> 6;
    const int bn = blockIdx.x & 63;
    const int m0 = bm << 6, n0 = bn << 6;
    const int tx = t & 15, ty = t >> 4;
    const int lm = t >> 2;
    const int lk = (t & 3) << 2;

    float acc[4][4] = {};
    for (int k0 = 0; k0 < 1024; k0 += 16) {
        f32x4 av = *(const f32x4*)(x    + (size_t)(m0 + lm) * 1024 + k0 + lk);
        f32x4 bv = *(const f32x4*)(W_ih + (size_t)(n0 + lm) * 1024 + k0 + lk);
        __syncthreads();
#pragma unroll
        for (int j = 0; j < 4; ++j) { a_s[lk + j][lm] = av[j]; b_s[lk + j][lm] = bv[j]; }
        __syncthreads();
#pragma unroll
        for (int k = 0; k < 16; ++k) {
            f32x4 af = *(const f32x4*)&a_s[k][4 * ty];
            f32x4 bf = *(const f32x4*)&b_s[k][4 * tx];
#pragma unroll
            for (int i = 0; i < 4; ++i)
#pragma unroll
                for (int j = 0; j < 4; ++j) acc[i][j] += af[i] * bf[j];
        }
    }
    f32x4 bi = *(const f32x4*)&b_ih[n0 + 4 * tx];
    f32x4 bh = *(const f32x4*)&b_hh[n0 + 4 * tx];
#pragma unroll
    for (int j = 0; j < 4; ++j) {
        const int n = n0 + 4 * tx + j;
        const float bias = bi[j] + bh[j];
        const int q = n >> 10, cidx = n & 1023;
        const int bg = cidx >> 2, r = cidx & 3;
#pragma unroll
        for (int i = 0; i < 4; ++i) {
            const int m = m0 + 4 * ty + i;
            gxT[((size_t)bg * T_STEPS + m) * 16 + r * 4 + q] = acc[i][j] + bias;
        }
    }
}

// ======== phase 2: R8's publish/poll verbatim + lean loop, UNPINNED whh ========
// whh is the ONLY large register array (R1/R3/R8 precedent: the allocator
// keeps one unpinned 64-VGPR array resident; pins cause AGPR/scratch spills
// — R4/R9). No wih, no x in the loop: per-step global reads = one 64B gx
// line (L2/L3, prefetch dist 2, broadcast dwordx4 per wave). Poll's vmcnt(0)
// now drains only that light prefetch instead of a 4KB HBM x-row.
__global__ __launch_bounds__(NTHR, 1)
void lstm_loop(const float* __restrict__ W_hh,
               const float* __restrict__ h0,
               const float* __restrict__ c0,
               const float* __restrict__ gxT,
               float* __restrict__ out,
               unsigned int* __restrict__ ring)
{
    __shared__ float h_lds[2][HDIM];

    const int tid = threadIdx.x;
    const int w   = tid >> 6;   // wave 0..3
    const int l   = tid & 63;   // lane
    const int u   = (blockIdx.x << 2) + w;

    // whh: lane l covers elements 4l + 256i — 64 VGPRs, unpinned
    f32x4 whh[16];
#pragma unroll
    for (int q = 0; q < 4; ++q) {
        const float* rh = W_hh + (size_t)(q * HDIM + u) * HDIM + 4 * l;
#pragma unroll
        for (int i = 0; i < 4; ++i) whh[q * 4 + i] = *(const f32x4*)(rh + 256 * i);
    }

    float c = c0[u];  // replicated across the wave
    f32x4 hr[4];
#pragma unroll
    for (int i = 0; i < 4; ++i) hr[i] = *(const f32x4*)(h0 + 4 * l + 256 * i);

    // gx pipeline: wave w broadcasts-loads its unit's 16B {g_i,g_f,g_c,g_o}
    const float* gxb = gxT + ((size_t)blockIdx.x * T_STEPS) * 16 + 4 * w;
    f32x4 gxA = *(const f32x4*)(gxb);        // t = 0
    f32x4 gxB = *(const f32x4*)(gxb + 16);   // t = 1
    f32x4 gxC;

    for (int t = 0; t < T_STEPS; ++t) {
        // gates = gx + whh . h_{t-1}
        float acc[4];
#pragma unroll
        for (int q = 0; q < 4; ++q) {
            float a = 0.f;
#pragma unroll
            for (int i = 0; i < 4; ++i) a += dot4(whh[q * 4 + i], hr[i]);
            acc[q] = a;
        }
#pragma unroll
        for (int m = 1; m < 64; m <<= 1) {
#pragma unroll
            for (int q = 0; q < 4; ++q) acc[q] += __shfl_xor(acc[q], m, 64);
        }
        const float gi = sigmoidf_(acc[0] + gxA[0]);
        const float gf = sigmoidf_(acc[1] + gxA[1]);
        const float gg = tanhf_   (acc[2] + gxA[2]);
        const float go = sigmoidf_(acc[3] + gxA[3]);
        c = gf * c + gi * gg;
        const float hval = go * tanhf_(c);   // identical on all 64 lanes

        if (l == 0) {
            // publish FIRST into this block's private 64B line (R8 layout)
            const unsigned pk = ((unsigned)(t + 1) << 16) | bf16_rne(hval);
            unsigned int* slot = ring + (((t & 1) * NBLK + blockIdx.x) << 4) + w;
            asm volatile("global_store_dword %0, %1, off sc0 sc1"
                         :: "v"((unsigned long long)slot), "v"(pk) : "memory");
        }
        if (l == 1) out[(size_t)t * HDIM + u] = hval;   // off the publish path
        if (t == T_STEPS - 1) break;

        // prefetch gx[t+2]: one 64B L2/L3 line, absorbed by the poll's vmcnt
        {
            const int tn = (t + 2 < T_STEPS) ? (t + 2) : (T_STEPS - 1);
            gxC = *(const f32x4*)(gxb + (size_t)tn * 16);
        }

        // wait for h_t: R8's poll verbatim — thread tid polls block tid's line
        {
            const unsigned e = (unsigned)(t + 1);
            const unsigned long long base =
                (unsigned long long)(ring + (((t & 1) * NBLK + tid) << 4));
            u32x4 p;
            for (;;) {
                asm volatile(
                    "global_load_dwordx4 %0, %1, off sc0 sc1\n\t"
                    "s_waitcnt vmcnt(0)"
                    : "=&v"(p)
                    : "v"(base)
                    : "memory");
                if ((p[0] >> 16) == e && (p[1] >> 16) == e &&
                    (p[2] >> 16) == e && (p[3] >> 16) == e) break;
            }
            const int ns = (t + 1) & 1;
            f32x4 hv;
            hv[0] = __uint_as_float(p[0] << 16);
            hv[1] = __uint_as_float(p[1] << 16);
            hv[2] = __uint_as_float(p[2] << 16);
            hv[3] = __uint_as_float(p[3] << 16);
            *(f32x4*)&h_lds[ns][4 * tid] = hv;   // units 4*tid .. 4*tid+3
        }
        __syncthreads();
        {
            const int ns = (t + 1) & 1;
#pragma unroll
            for (int i = 0; i < 4; ++i)
                hr[i] = *(const f32x4*)&h_lds[ns][4 * l + 256 * i];
        }
        gxA = gxB; gxB = gxC;
    }
}

extern "C" void kernel_launch(void* const* d_in, const int* in_sizes, int n_in,
                              void* d_out, int out_size, void* d_ws, size_t ws_size,
                              hipStream_t stream)
{
    const float* x    = (const float*)d_in[0];
    const float* W_ih = (const float*)d_in[1];
    const float* W_hh = (const float*)d_in[2];
    const float* b_ih = (const float*)d_in[3];
    const float* b_hh = (const float*)d_in[4];
    const float* h0   = (const float*)d_in[5];
    const float* c0   = (const float*)d_in[6];

    unsigned int* ring = (unsigned int*)d_ws;
    float* gxT = (float*)((char*)d_ws + (1u << 20));

    hipMemsetAsync(d_ws, 0, 2 * NBLK * 16 * sizeof(unsigned int), stream);
    gemm_gx<<<8192, 256, 0, stream>>>(x, W_ih, b_ih, b_hh, gxT);
    lstm_loop<<<NBLK, 256, 0, stream>>>(W_hh, h0, c0, gxT, (float*)d_out, ring);
}

// Round 12
// 26648.984 us; speedup vs baseline: 1.0384x; 1.0384x over previous
//
#include <hip/hip_runtime.h>
#include <cstdint>

#define T_STEPS 8192
#define HDIM    1024
#define NBLK    256
#define NTHR    320   // waves 0-3 compute, wave 4 = relay/poller

typedef float        f32x4 __attribute__((ext_vector_type(4)));
typedef unsigned int u32x4 __attribute__((ext_vector_type(4)));

__device__ __forceinline__ float dot4(f32x4 a, f32x4 b) {
    return a[0] * b[0] + a[1] * b[1] + a[2] * b[2] + a[3] * b[3];
}
__device__ __forceinline__ float sigmoidf_(float v) { return 1.0f / (1.0f + __expf(-v)); }
__device__ __forceinline__ float tanhf_(float v)    { return 1.0f - 2.0f / (__expf(2.0f * v) + 1.0f); }
__device__ __forceinline__ unsigned bf16_rne(float f) {
    unsigned b = __float_as_uint(f);
    return (b + 0x7FFFu + ((b >> 16) & 1u)) >> 16;
}

// R8's fused compute structure + writer-private ring (22.3ms, best so far),
// restructured with a DEDICATED RELAY WAVE:
//  - waves 0-3: gates/publish/prefetch/gxp exactly as R8, but NEVER poll.
//    Their prefetch drains happen inside s_barrier wait — off detect path.
//  - wave 4: owns no unit; its ONLY memory ops are the 4 poll dwordx4
//    (covering all 256 writer-private lines), so its vmcnt(0) is a pure
//    ~600cy ring RT. Writes h into LDS for everyone.
// GPU-wide poll traffic drops 4x (65536 -> 16384 pollers) — R8's residual
// was poll-queueing against publish stores (tail gates every step) plus
// per-thread prefetch drain inside the detect vmcnt.
__global__ __launch_bounds__(NTHR, 1)
void lstm_persistent(const float* __restrict__ x,
                     const float* __restrict__ W_ih,
                     const float* __restrict__ W_hh,
                     const float* __restrict__ b_ih,
                     const float* __restrict__ b_hh,
                     const float* __restrict__ h0,
                     const float* __restrict__ c0,
                     float* __restrict__ out,
                     unsigned int* __restrict__ ring)
{
    __shared__ float h_lds[2][HDIM];

    const int tid = threadIdx.x;
    const int w   = tid >> 6;   // wave 0..4
    const int l   = tid & 63;   // lane
    const int u   = (blockIdx.x << 2) + w;   // valid for w<4 only

    f32x4 whh[16], wih[16];
    float bias[4] = {};
    float c = 0.f;
    f32x4 hr[4] = {};
    float gxp[4] = {};
    f32x4 xr[4] = {}, xn[4] = {};

    if (w < 4) {
        // ---- weights: lane l covers elements 4l + 256i (+j) ----
#pragma unroll
        for (int q = 0; q < 4; ++q) {
            const float* rh = W_hh + (size_t)(q * HDIM + u) * HDIM + 4 * l;
            const float* ri = W_ih + (size_t)(q * HDIM + u) * HDIM + 4 * l;
#pragma unroll
            for (int i = 0; i < 4; ++i) {
                whh[q * 4 + i] = *(const f32x4*)(rh + 256 * i);
                wih[q * 4 + i] = *(const f32x4*)(ri + 256 * i);
            }
        }
#pragma unroll
        for (int k = 0; k < 16; ++k) {
            asm volatile("" : "+v"(whh[k]));
            asm volatile("" : "+v"(wih[k]));
        }
#pragma unroll
        for (int q = 0; q < 4; ++q) bias[q] = b_ih[q * HDIM + u] + b_hh[q * HDIM + u];
        c = c0[u];
#pragma unroll
        for (int i = 0; i < 4; ++i) hr[i] = *(const f32x4*)(h0 + 4 * l + 256 * i);
        {
            f32x4 x0[4];
#pragma unroll
            for (int i = 0; i < 4; ++i) x0[i] = *(const f32x4*)(x + 4 * l + 256 * i);
#pragma unroll
            for (int q = 0; q < 4; ++q) {
                float a = 0.f;
#pragma unroll
                for (int i = 0; i < 4; ++i) a += dot4(wih[q * 4 + i], x0[i]);
                gxp[q] = a;
            }
        }
#pragma unroll
        for (int i = 0; i < 4; ++i) xr[i] = *(const f32x4*)(x + HDIM + 4 * l + 256 * i);
    }

    const unsigned long long ringb = (unsigned long long)ring;

    for (int t = 0; t < T_STEPS; ++t) {
        if (w < 4) {
            // gates = gxp + Whh . h_{t-1}
            float acc[4];
#pragma unroll
            for (int q = 0; q < 4; ++q) {
                float a = gxp[q];
#pragma unroll
                for (int i = 0; i < 4; ++i) a += dot4(whh[q * 4 + i], hr[i]);
                acc[q] = a;
            }
#pragma unroll
            for (int m = 1; m < 64; m <<= 1) {
#pragma unroll
                for (int q = 0; q < 4; ++q) acc[q] += __shfl_xor(acc[q], m, 64);
            }
            const float gi = sigmoidf_(acc[0] + bias[0]);
            const float gf = sigmoidf_(acc[1] + bias[1]);
            const float gg = tanhf_   (acc[2] + bias[2]);
            const float go = sigmoidf_(acc[3] + bias[3]);
            c = gf * c + gi * gg;
            const float hval = go * tanhf_(c);

            if (l == 0) {
                // publish into this block's private 64B line
                const unsigned pk = ((unsigned)(t + 1) << 16) | bf16_rne(hval);
                unsigned int* slot =
                    ring + (((t & 1) * NBLK + blockIdx.x) << 4) + w;
                asm volatile("global_store_dword %0, %1, off sc0 sc1"
                             :: "v"((unsigned long long)slot), "v"(pk) : "memory");
            }
            if (l == 1) out[(size_t)t * HDIM + u] = hval;
        }
        if (t == T_STEPS - 1) break;

        if (w < 4) {
            // x[t+2] prefetch — drains inside the barrier wait, not a poll
            const int tn = (t + 2 < T_STEPS) ? (t + 2) : (T_STEPS - 1);
            const float* xp = x + (size_t)tn * HDIM;
#pragma unroll
            for (int i = 0; i < 4; ++i) xn[i] = *(const f32x4*)(xp + 4 * l + 256 * i);
            // gx partials for step t+1 (independent of h_t)
#pragma unroll
            for (int q = 0; q < 4; ++q) {
                float a = 0.f;
#pragma unroll
                for (int i = 0; i < 4; ++i) a += dot4(wih[q * 4 + i], xr[i]);
                gxp[q] = a;
            }
        } else {
            // ---- relay: lane l polls lines {l, l+64, l+128, l+192} ----
            const unsigned e = (unsigned)(t + 1);
            const unsigned long long pb =
                ringb + (unsigned long long)((t & 1) * 16384 + (l << 6));
            const unsigned long long a0 = pb;
            const unsigned long long a1 = pb + 4096;
            const unsigned long long a2 = pb + 8192;
            const unsigned long long a3 = pb + 12288;
            u32x4 p0, p1, p2, p3;
            for (;;) {
                asm volatile(
                    "global_load_dwordx4 %0, %4, off sc0 sc1\n\t"
                    "global_load_dwordx4 %1, %5, off sc0 sc1\n\t"
                    "global_load_dwordx4 %2, %6, off sc0 sc1\n\t"
                    "global_load_dwordx4 %3, %7, off sc0 sc1\n\t"
                    "s_waitcnt vmcnt(0)"
                    : "=&v"(p0), "=&v"(p1), "=&v"(p2), "=&v"(p3)
                    : "v"(a0), "v"(a1), "v"(a2), "v"(a3)
                    : "memory");
                const bool ok =
                    (p0[0] >> 16) == e && (p0[1] >> 16) == e &&
                    (p0[2] >> 16) == e && (p0[3] >> 16) == e &&
                    (p1[0] >> 16) == e && (p1[1] >> 16) == e &&
                    (p1[2] >> 16) == e && (p1[3] >> 16) == e &&
                    (p2[0] >> 16) == e && (p2[1] >> 16) == e &&
                    (p2[2] >> 16) == e && (p2[3] >> 16) == e &&
                    (p3[0] >> 16) == e && (p3[1] >> 16) == e &&
                    (p3[2] >> 16) == e && (p3[3] >> 16) == e;
                if (ok) break;
                __builtin_amdgcn_s_sleep(1);
            }
            const int ns = (t + 1) & 1;
            f32x4 hv;
#pragma unroll
            for (int j = 0; j < 4; ++j) hv[j] = __uint_as_float(p0[j] << 16);
            *(f32x4*)&h_lds[ns][4 * l] = hv;
#pragma unroll
            for (int j = 0; j < 4; ++j) hv[j] = __uint_as_float(p1[j] << 16);
            *(f32x4*)&h_lds[ns][4 * l + 256] = hv;
#pragma unroll
            for (int j = 0; j < 4; ++j) hv[j] = __uint_as_float(p2[j] << 16);
            *(f32x4*)&h_lds[ns][4 * l + 512] = hv;
#pragma unroll
            for (int j = 0; j < 4; ++j) hv[j] = __uint_as_float(p3[j] << 16);
            *(f32x4*)&h_lds[ns][4 * l + 768] = hv;
        }
        __syncthreads();
        if (w < 4) {
            const int ns = (t + 1) & 1;
#pragma unroll
            for (int i = 0; i < 4; ++i)
                hr[i] = *(const f32x4*)&h_lds[ns][4 * l + 256 * i];
#pragma unroll
            for (int i = 0; i < 4; ++i) xr[i] = xn[i];
        }
    }
}

extern "C" void kernel_launch(void* const* d_in, const int* in_sizes, int n_in,
                              void* d_out, int out_size, void* d_ws, size_t ws_size,
                              hipStream_t stream)
{
    const float* x    = (const float*)d_in[0];
    const float* W_ih = (const float*)d_in[1];
    const float* W_hh = (const float*)d_in[2];
    const float* b_ih = (const float*)d_in[3];
    const float* b_hh = (const float*)d_in[4];
    const float* h0   = (const float*)d_in[5];
    const float* c0   = (const float*)d_in[6];

    unsigned int* ring = (unsigned int*)d_ws;
    hipMemsetAsync(d_ws, 0, 2 * NBLK * 16 * sizeof(unsigned int), stream);
    lstm_persistent<<<NBLK, NTHR, 0, stream>>>(x, W_ih, W_hh, b_ih, b_hh, h0, c0,
                                               (float*)d_out, ring);
}